// Round 7
// baseline (101.501 us; speedup 1.0000x reference)
//
#include <hip/hip_runtime.h>
#include <hip/hip_bf16.h>
#include <stdint.h>

#define N 8192
#define D 256
#define ROWB 256                      // rows per simlse block (4 waves x 64)
#define COLG 32                       // column groups
#define COLS_PER_BLK (N / COLG)       // 256
#define TILE_N 16
#define NT (COLS_PER_BLK / TILE_N)    // 16
#define TILE_BYTES (TILE_N * D * 2)   // 8192 B
#define NBUF 4                        // 32 KB LDS ring
#define E_CONST 2.71828182845904523536f
#define LOG2E 1.44269504088896340736f

typedef __attribute__((ext_vector_type(8))) short bf16x8;   // 8 bf16 (4 VGPRs)
typedef __attribute__((ext_vector_type(4))) float f32x4;

__device__ inline float bf2f(unsigned short u) {
  union { unsigned int i; float f; } c; c.i = ((unsigned)u) << 16; return c.f;
}
__device__ inline unsigned short f2bf(float x) {
  union { float f; unsigned int i; } c; c.f = x;
  unsigned int r = (c.i + 0x7fffu + ((c.i >> 16) & 1u)) >> 16;
  return (unsigned short)r;
}

typedef const __attribute__((address_space(1))) void gvoid_t;
typedef __attribute__((address_space(3))) void lvoid_t;
__device__ inline void gload_lds16(const void* g, void* l) {
  __builtin_amdgcn_global_load_lds((gvoid_t*)g, (lvoid_t*)l, 16, 0, 0);
}

// ---- kernel 1: row L2-normalize, fp32 -> bf16 (plain + log2e-scaled copies) ----
__global__ __launch_bounds__(256) void norm_kernel(const float* __restrict__ feat,
                                                   unsigned short* __restrict__ fbf,
                                                   unsigned short* __restrict__ fbfA) {
  int wave = threadIdx.x >> 6, lane = threadIdx.x & 63;
  int row = blockIdx.x * 4 + wave;
  const float4 v = *(const float4*)(feat + (size_t)row * D + lane * 4);
  float ss = v.x * v.x + v.y * v.y + v.z * v.z + v.w * v.w;
  for (int m = 1; m < 64; m <<= 1) ss += __shfl_xor(ss, m, 64);
  float rn = 1.0f / fmaxf(sqrtf(ss), 1e-12f);
  ushort4 o;
  o.x = f2bf(v.x * rn); o.y = f2bf(v.y * rn);
  o.z = f2bf(v.z * rn); o.w = f2bf(v.w * rn);
  *(ushort4*)(fbf + (size_t)row * D + lane * 4) = o;
  float rl = rn * LOG2E;
  ushort4 oa;
  oa.x = f2bf(v.x * rl); oa.y = f2bf(v.y * rl);
  oa.z = f2bf(v.z * rl); oa.w = f2bf(v.w * rl);
  *(ushort4*)(fbfA + (size_t)row * D + lane * 4) = oa;
}

// ---- kernel 2: positive-pair dot (unscaled normalized rows) ----
__global__ __launch_bounds__(256) void pos_kernel(const unsigned short* __restrict__ fbf,
                                                  float* __restrict__ pos) {
  int wave = threadIdx.x >> 6, lane = threadIdx.x & 63;
  int row = blockIdx.x * 4 + wave;
  int partner = (row < N / 2) ? row + N / 2 : row - N / 2;
  const ushort4 a = *(const ushort4*)(fbf + (size_t)row * D + lane * 4);
  const ushort4 b = *(const ushort4*)(fbf + (size_t)partner * D + lane * 4);
  float d = bf2f(a.x) * bf2f(b.x) + bf2f(a.y) * bf2f(b.y) +
            bf2f(a.z) * bf2f(b.z) + bf2f(a.w) * bf2f(b.w);
  for (int m = 1; m < 64; m <<= 1) d += __shfl_xor(d, m, 64);
  if (lane == 0) pos[row] = d;
}

// ---- kernel 3: fused sim tile + partial sum(2^(sim*log2e)) = sum(exp(sim)) ----
// M=64 rows/wave (4 m-tiles); TILE_N=16; 4-deep 32KB LDS ring; one barrier/tile;
// counted vmcnt; slab output (one writer per entry, no atomics).
__global__ __launch_bounds__(256, 3) void simlse_kernel(const unsigned short* __restrict__ fbfA,
                                                        const unsigned short* __restrict__ fbf,
                                                        float* __restrict__ slab) {
  __shared__ char lds[NBUF * TILE_BYTES];   // 32 KB
  const char* fb = (const char*)fbf;
  const char* fa = (const char*)fbfA;
  int tid = threadIdx.x;
  int wave = tid >> 6, lane = tid & 63;
  int l15 = lane & 15, lhi = lane >> 4;
  int rb = blockIdx.x >> 5;   // 0..31
  int cg = blockIdx.x & 31;   // 0..31

  // A fragments (log2e-scaled): 4 m-tiles (64 rows/wave) x 8 k-steps, pinned
  bf16x8 a[4][8];
  int rowbase = rb * ROWB + wave * 64;
#pragma unroll
  for (int mt = 0; mt < 4; ++mt) {
    size_t ar = (size_t)(rowbase + mt * 16 + l15) * 512;
#pragma unroll
    for (int ks = 0; ks < 8; ++ks)
      a[mt][ks] = *(const bf16x8*)(fa + ar + lhi * 16 + ks * 64);
  }
#pragma unroll
  for (int mt = 0; mt < 4; ++mt)
#pragma unroll
    for (int ks = 0; ks < 8; ++ks)
      asm volatile("" : "+v"(a[mt][ks]));   // pin: forbid rematerialization / sinking

  float s[4][4];
#pragma unroll
  for (int mt = 0; mt < 4; ++mt)
#pragma unroll
    for (int r = 0; r < 4; ++r) s[mt][r] = 0.0f;

  // staging: 256 threads x 16B x 2 passes = one 8 KB tile; XOR-swizzled source
  int colbase = cg * COLS_PER_BLK;
  int o0 = tid * 16;            // 0..4095
  int o1 = o0 + 4096;
  int lrow0 = o0 >> 9, lrow1 = o1 >> 9;
  int goff0 = (o0 & 511) ^ ((lrow0 & 7) << 4);
  int goff1 = (o1 & 511) ^ ((lrow1 & 7) << 4);

#define STAGE(tt)                                                              \
  {                                                                            \
    char* stg = lds + ((tt) & (NBUF - 1)) * TILE_BYTES;                        \
    size_t cb = (size_t)(colbase + (tt) * TILE_N);                             \
    gload_lds16(fb + (cb + lrow0) * 512 + goff0, stg + wave * 1024);           \
    gload_lds16(fb + (cb + lrow1) * 512 + goff1, stg + 4096 + wave * 1024);    \
  }

  STAGE(0);
  STAGE(1);

  for (int t = 0; t < NT; ++t) {
    if (t + 2 < NT) {
      STAGE(t + 2);                       // ring distance 3 from any live reader
      asm volatile("s_waitcnt vmcnt(4)" ::: "memory");  // tile t landed
    } else if (t + 1 < NT) {
      asm volatile("s_waitcnt vmcnt(2)" ::: "memory");
    } else {
      asm volatile("s_waitcnt vmcnt(0)" ::: "memory");
    }
    __builtin_amdgcn_sched_barrier(0);
    __builtin_amdgcn_s_barrier();         // all waves' chunks of tile t visible
    __builtin_amdgcn_sched_barrier(0);

    const char* bb = lds + (t & (NBUF - 1)) * TILE_BYTES;
    int rswz = (l15 & 7) << 4;
    f32x4 acc0 = {0,0,0,0}, acc1 = {0,0,0,0}, acc2 = {0,0,0,0}, acc3 = {0,0,0,0};
    const char* br = bb + l15 * 512;
#pragma unroll
    for (int ks = 0; ks < 8; ++ks) {
      int kb = lhi * 16 + ks * 64;
      bf16x8 bfrag = *(const bf16x8*)(br + (kb ^ rswz));
      acc0 = __builtin_amdgcn_mfma_f32_16x16x32_bf16(a[0][ks], bfrag, acc0, 0, 0, 0);
      acc1 = __builtin_amdgcn_mfma_f32_16x16x32_bf16(a[1][ks], bfrag, acc1, 0, 0, 0);
      acc2 = __builtin_amdgcn_mfma_f32_16x16x32_bf16(a[2][ks], bfrag, acc2, 0, 0, 0);
      acc3 = __builtin_amdgcn_mfma_f32_16x16x32_bf16(a[3][ks], bfrag, acc3, 0, 0, 0);
    }
#pragma unroll
    for (int r = 0; r < 4; ++r) {
      s[0][r] += __builtin_exp2f(acc0[r]);
      s[1][r] += __builtin_exp2f(acc1[r]);
      s[2][r] += __builtin_exp2f(acc2[r]);
      s[3][r] += __builtin_exp2f(acc3[r]);
    }
  }
#undef STAGE

  // row-wise reduce across the 16 lanes holding each row's columns
#pragma unroll
  for (int mt = 0; mt < 4; ++mt)
#pragma unroll
    for (int r = 0; r < 4; ++r)
      for (int m = 1; m < 16; m <<= 1)
        s[mt][r] += __shfl_xor(s[mt][r], m, 64);

  if (l15 == 0) {
#pragma unroll
    for (int mt = 0; mt < 4; ++mt)
#pragma unroll
      for (int r = 0; r < 4; ++r)
        slab[(size_t)cg * N + rowbase + mt * 16 + lhi * 4 + r] = s[mt][r];
  }
}

// ---- kernel 4: combine slab -> scalar loss (64 blocks, coalesced) ----
__global__ __launch_bounds__(128) void final_kernel(const float* __restrict__ slab,
                                                    const float* __restrict__ pos,
                                                    float* __restrict__ out) {
  int tid = threadIdx.x;
  int row = blockIdx.x * 128 + tid;
  float ssum = 0.0f;
#pragma unroll
  for (int c = 0; c < COLG; ++c) ssum += slab[(size_t)c * N + row];
  float v = __logf(ssum - E_CONST) - pos[row];   // remove diag exp(sim_ii) ~= e
  for (int m = 1; m < 64; m <<= 1) v += __shfl_xor(v, m, 64);
  __shared__ float r2[2];
  if ((tid & 63) == 0) r2[tid >> 6] = v;
  __syncthreads();
  if (tid == 0) atomicAdd(out, (r2[0] + r2[1]) * (1.0f / (float)N));
}

extern "C" void kernel_launch(void* const* d_in, const int* in_sizes, int n_in,
                              void* d_out, int out_size, void* d_ws, size_t ws_size,
                              hipStream_t stream) {
  const float* feat = (const float*)d_in[0];
  unsigned short* fbf  = (unsigned short*)d_ws;                                  // 4 MB
  unsigned short* fbfA = (unsigned short*)((char*)d_ws + (size_t)N * D * 2);     // 4 MB
  float* pos  = (float*)((char*)d_ws + (size_t)2 * N * D * 2);                   // 32 KB
  float* slab = (float*)((char*)d_ws + (size_t)2 * N * D * 2 + (size_t)N * 4);   // 1 MB
  float* out = (float*)d_out;

  hipMemsetAsync(out, 0, sizeof(float), stream);
  norm_kernel<<<N / 4, 256, 0, stream>>>(feat, fbf, fbfA);
  pos_kernel<<<N / 4, 256, 0, stream>>>(fbf, pos);
  simlse_kernel<<<(N / ROWB) * COLG, 256, 0, stream>>>(fbfA, fbf, slab);
  final_kernel<<<N / 128, 128, 0, stream>>>(slab, pos, out);
}

// Round 8
// 61.784 us; speedup vs baseline: 1.6428x; 1.6428x over previous
//
#include <hip/hip_runtime.h>
#include <hip/hip_bf16.h>
#include <stdint.h>

#define N 8192
#define D 256
#define ROWB 128                      // rows per simlse block (4 waves x 32)
#define COLG 16                       // column groups
#define COLS_PER_BLK (N / COLG)       // 512
#define TILE_N 16
#define NT (COLS_PER_BLK / TILE_N)    // 32 tiles -> 16 pairs
#define TILE_BYTES (TILE_N * D * 2)   // 8192 B
#define NBUF 4                        // 32 KB LDS ring
#define E_CONST 2.71828182845904523536f

typedef __attribute__((ext_vector_type(8))) short bf16x8;   // 8 bf16 (4 VGPRs)
typedef __attribute__((ext_vector_type(4))) float f32x4;

__device__ inline float bf2f(unsigned short u) {
  union { unsigned int i; float f; } c; c.i = ((unsigned)u) << 16; return c.f;
}
__device__ inline unsigned short f2bf(float x) {
  union { float f; unsigned int i; } c; c.f = x;
  unsigned int r = (c.i + 0x7fffu + ((c.i >> 16) & 1u)) >> 16;
  return (unsigned short)r;
}

typedef const __attribute__((address_space(1))) void gvoid_t;
typedef __attribute__((address_space(3))) void lvoid_t;
__device__ inline void gload_lds16(const void* g, void* l) {
  __builtin_amdgcn_global_load_lds((gvoid_t*)g, (lvoid_t*)l, 16, 0, 0);
}

// ---- kernel 1: row L2-normalize, fp32 -> bf16 ----
__global__ __launch_bounds__(256) void norm_kernel(const float* __restrict__ feat,
                                                   unsigned short* __restrict__ fbf) {
  int wave = threadIdx.x >> 6, lane = threadIdx.x & 63;
  int row = blockIdx.x * 4 + wave;
  const float4 v = *(const float4*)(feat + (size_t)row * D + lane * 4);
  float ss = v.x * v.x + v.y * v.y + v.z * v.z + v.w * v.w;
  for (int m = 1; m < 64; m <<= 1) ss += __shfl_xor(ss, m, 64);
  float rn = 1.0f / fmaxf(sqrtf(ss), 1e-12f);
  ushort4 o;
  o.x = f2bf(v.x * rn); o.y = f2bf(v.y * rn);
  o.z = f2bf(v.z * rn); o.w = f2bf(v.w * rn);
  *(ushort4*)(fbf + (size_t)row * D + lane * 4) = o;
}

// ---- kernel 2: fused sim tile-pair + partial sum(exp(sim)); slab output ----
// R4 structure; pairs: one vmcnt(0)+barrier per 2 tiles; staging issued
// POST-barrier (all waves past barrier => previous pair's buffers free).
__global__ __launch_bounds__(256, 3) void simlse_kernel(const unsigned short* __restrict__ fbf,
                                                        float* __restrict__ slab) {
  __shared__ char lds[NBUF * TILE_BYTES];   // 32 KB
  const char* fb = (const char*)fbf;
  int tid = threadIdx.x;
  int wave = tid >> 6, lane = tid & 63;
  int l15 = lane & 15, lhi = lane >> 4;
  int rb = blockIdx.x >> 4;   // 0..63
  int cg = blockIdx.x & 15;   // 0..15

  // A fragments: 2 m-tiles (32 rows/wave) x 8 k-steps, pinned (live in acc file)
  bf16x8 a[2][8];
  int rowbase = rb * ROWB + wave * 32;
#pragma unroll
  for (int mt = 0; mt < 2; ++mt) {
    size_t ar = (size_t)(rowbase + mt * 16 + l15) * 512;
#pragma unroll
    for (int ks = 0; ks < 8; ++ks)
      a[mt][ks] = *(const bf16x8*)(fb + ar + lhi * 16 + ks * 64);
  }
#pragma unroll
  for (int mt = 0; mt < 2; ++mt)
#pragma unroll
    for (int ks = 0; ks < 8; ++ks)
      asm volatile("" : "+v"(a[mt][ks]));   // forbid rematerialization / sinking

  float s0[4] = {0, 0, 0, 0}, s1[4] = {0, 0, 0, 0};

  // staging: 256 threads x 16B x 2 passes = one 8 KB tile; XOR-swizzled source
  int colbase = cg * COLS_PER_BLK;
  int o0 = tid * 16;            // 0..4095
  int o1 = o0 + 4096;
  int lrow0 = o0 >> 9, lrow1 = o1 >> 9;
  int goff0 = (o0 & 511) ^ ((lrow0 & 7) << 4);
  int goff1 = (o1 & 511) ^ ((lrow1 & 7) << 4);
  int rswz = (l15 & 7) << 4;

#define STAGE(tt)                                                              \
  {                                                                            \
    char* stg = lds + ((tt) & (NBUF - 1)) * TILE_BYTES;                        \
    size_t cb = (size_t)(colbase + (tt) * TILE_N);                             \
    gload_lds16(fb + (cb + lrow0) * 512 + goff0, stg + wave * 1024);           \
    gload_lds16(fb + (cb + lrow1) * 512 + goff1, stg + 4096 + wave * 1024);    \
  }

#define COMPUTE(tt)                                                            \
  {                                                                            \
    const char* bb = lds + ((tt) & (NBUF - 1)) * TILE_BYTES + l15 * 512;       \
    f32x4 acc0 = {0, 0, 0, 0}, acc1 = {0, 0, 0, 0};                            \
    _Pragma("unroll")                                                          \
    for (int ks = 0; ks < 8; ++ks) {                                           \
      int kb = lhi * 16 + ks * 64;                                             \
      bf16x8 bfrag = *(const bf16x8*)(bb + (kb ^ rswz));                       \
      acc0 = __builtin_amdgcn_mfma_f32_16x16x32_bf16(a[0][ks], bfrag, acc0, 0, 0, 0); \
      acc1 = __builtin_amdgcn_mfma_f32_16x16x32_bf16(a[1][ks], bfrag, acc1, 0, 0, 0); \
    }                                                                          \
    _Pragma("unroll")                                                          \
    for (int r = 0; r < 4; ++r) {                                              \
      s0[r] += __expf(acc0[r]);                                                \
      s1[r] += __expf(acc1[r]);                                                \
    }                                                                          \
  }

  STAGE(0);
  STAGE(1);

  const int NP = NT / 2;   // 16 pairs
  for (int u = 0; u < NP; ++u) {
    asm volatile("s_waitcnt vmcnt(0)" ::: "memory");   // this pair's tiles landed
    __builtin_amdgcn_sched_barrier(0);
    __builtin_amdgcn_s_barrier();                      // all waves' chunks visible
    __builtin_amdgcn_sched_barrier(0);
    if (u + 1 < NP) {       // post-barrier staging: prev pair's buffers are free
      STAGE(2 * u + 2);
      STAGE(2 * u + 3);
    }
    COMPUTE(2 * u);
    COMPUTE(2 * u + 1);
  }
#undef STAGE
#undef COMPUTE

  // row-wise reduce across the 16 lanes holding each row's columns
#pragma unroll
  for (int r = 0; r < 4; ++r)
    for (int m = 1; m < 16; m <<= 1) {
      s0[r] += __shfl_xor(s0[r], m, 64);
      s1[r] += __shfl_xor(s1[r], m, 64);
    }
  if (l15 == 0) {
    float* dst = slab + (size_t)cg * N + rowbase + lhi * 4;
#pragma unroll
    for (int r = 0; r < 4; ++r) { dst[r] = s0[r]; dst[16 + r] = s1[r]; }
  }
}

// ---- kernel 3: pos-dot + combine slab -> scalar loss (fused, grid 32) ----
__global__ __launch_bounds__(256) void final_kernel(const unsigned short* __restrict__ fbf,
                                                    const float* __restrict__ slab,
                                                    float* __restrict__ out) {
  __shared__ float pl[256];
  __shared__ float r4[4];
  int tid = threadIdx.x;
  int row0 = blockIdx.x * 256;

  // pos phase: 4 lanes per row, 64 rows per pass, 4 passes
#pragma unroll
  for (int pass = 0; pass < 4; ++pass) {
    int r = row0 + pass * 64 + (tid >> 2);
    int p = r ^ 4096;                           // partner index (N/2 = 4096)
    const bf16x8* ra = (const bf16x8*)(fbf + (size_t)r * D) + (tid & 3) * 8;
    const bf16x8* rb = (const bf16x8*)(fbf + (size_t)p * D) + (tid & 3) * 8;
    float d = 0.0f;
#pragma unroll
    for (int j = 0; j < 8; ++j) {
      bf16x8 va = ra[j], vb = rb[j];
#pragma unroll
      for (int e = 0; e < 8; ++e)
        d += bf2f((unsigned short)va[e]) * bf2f((unsigned short)vb[e]);
    }
    d += __shfl_xor(d, 1, 64);
    d += __shfl_xor(d, 2, 64);
    if ((tid & 3) == 0) pl[pass * 64 + (tid >> 2)] = d;
  }
  __syncthreads();

  int row = row0 + tid;
  float ssum = 0.0f;
#pragma unroll
  for (int c = 0; c < COLG; ++c) ssum += slab[(size_t)c * N + row];
  float v = __logf(ssum - E_CONST) - pl[tid];   // remove diag exp(sim_ii) ~= e
  for (int m = 1; m < 64; m <<= 1) v += __shfl_xor(v, m, 64);
  if ((tid & 63) == 0) r4[tid >> 6] = v;
  __syncthreads();
  if (tid == 0)
    atomicAdd(out, (r4[0] + r4[1] + r4[2] + r4[3]) * (1.0f / (float)N));
}

extern "C" void kernel_launch(void* const* d_in, const int* in_sizes, int n_in,
                              void* d_out, int out_size, void* d_ws, size_t ws_size,
                              hipStream_t stream) {
  const float* feat = (const float*)d_in[0];
  unsigned short* fbf = (unsigned short*)d_ws;                                 // 4 MB
  float* slab = (float*)((char*)d_ws + (size_t)N * D * 2);                     // 512 KB
  float* out = (float*)d_out;

  hipMemsetAsync(out, 0, sizeof(float), stream);
  norm_kernel<<<N / 4, 256, 0, stream>>>(feat, fbf);
  simlse_kernel<<<(N / ROWB) * COLG, 256, 0, stream>>>(fbf, slab);
  final_kernel<<<N / 256, 256, 0, stream>>>(fbf, slab, out);
}

// Round 9
// 42.899 us; speedup vs baseline: 2.3660x; 1.4402x over previous
//
#include <hip/hip_runtime.h>
#include <hip/hip_bf16.h>
#include <stdint.h>

#define N 8192
#define D 256                          // fp8 row = 256 bytes
#define ROWB 128                       // rows per simlse block (4 waves x 32)
#define COLG 16                        // column groups
#define COLS_PER_BLK (N / COLG)        // 512
#define CTILE 32                       // cols per tile
#define NT (COLS_PER_BLK / CTILE)      // 16 tiles -> 8 pairs
#define TILE_BYTES (CTILE * D)         // 8192 B
#define NBUF 4                         // 32 KB LDS ring
#define E_CONST 2.71828182845904523536f

typedef __attribute__((ext_vector_type(4))) int i32x4;
typedef __attribute__((ext_vector_type(8))) int i32x8;
typedef __attribute__((ext_vector_type(16))) float f32x16;

typedef const __attribute__((address_space(1))) void gvoid_t;
typedef __attribute__((address_space(3))) void lvoid_t;
__device__ inline void gload_lds16(const void* g, void* l) {
  __builtin_amdgcn_global_load_lds((gvoid_t*)g, (lvoid_t*)l, 16, 0, 0);
}

// fp32 -> e4m3fn (RNE), manual fallback if builtin missing
#if !__has_builtin(__builtin_amdgcn_cvt_pk_fp8_f32)
__device__ inline unsigned int f2e4m3(float x) {
  union { float f; unsigned u; } c; c.f = x;
  unsigned s = (c.u >> 31) << 7;
  float ax = fabsf(x);
  if (!(ax > 0.0f)) return s;
  if (ax >= 448.0f) return s | 0x7E;
  int e; float m = frexpf(ax, &e);      // ax = m * 2^e, m in [0.5,1)
  int E = e - 1 + 7;
  if (E <= 0) {                          // subnormal, unit 2^-9
    int qi = (int)rintf(ax * 512.0f);
    if (qi > 7) return s | 0x08;
    return s | (unsigned)qi;
  }
  int qi = (int)rintf(m * 16.0f);        // [8,16]
  if (qi == 16) { qi = 8; E += 1; }
  if (E > 15) return s | 0x7E;
  return s | (unsigned)((E << 3) | (qi - 8));
}
#endif

// ---- kernel 1: row L2-normalize, fp32 -> fp8 e4m3; store 1/norm ----
__global__ __launch_bounds__(256) void norm_kernel(const float* __restrict__ feat,
                                                   unsigned char* __restrict__ f8,
                                                   float* __restrict__ rnorm) {
  int wave = threadIdx.x >> 6, lane = threadIdx.x & 63;
  int row = blockIdx.x * 4 + wave;
  const float4 v = *(const float4*)(feat + (size_t)row * D + lane * 4);
  float ss = v.x * v.x + v.y * v.y + v.z * v.z + v.w * v.w;
  for (int m = 1; m < 64; m <<= 1) ss += __shfl_xor(ss, m, 64);
  float rn = 1.0f / fmaxf(sqrtf(ss), 1e-12f);
  if (lane == 0) rnorm[row] = rn;
#if __has_builtin(__builtin_amdgcn_cvt_pk_fp8_f32)
  int p = __builtin_amdgcn_cvt_pk_fp8_f32(v.x * rn, v.y * rn, 0, 0);
  p = __builtin_amdgcn_cvt_pk_fp8_f32(v.z * rn, v.w * rn, p, 1);
#else
  int p = (int)(f2e4m3(v.x * rn) | (f2e4m3(v.y * rn) << 8) |
                (f2e4m3(v.z * rn) << 16) | (f2e4m3(v.w * rn) << 24));
#endif
  *(int*)(f8 + (size_t)row * D + lane * 4) = p;
}

// ---- kernel 2: fused fp8 sim + partial sum(exp(sim)); slab output ----
// 32x32x64 MX MFMA (scale=1.0). R8 pair schedule: one vmcnt(0)+barrier per
// 2 tiles, staging post-barrier, 4-deep 32KB LDS ring, both-sides XOR swizzle.
__global__ __launch_bounds__(256, 3) void simlse_kernel(const unsigned char* __restrict__ f8,
                                                        float* __restrict__ slab) {
  __shared__ char lds[NBUF * TILE_BYTES];   // 32 KB
  const char* fb = (const char*)f8;
  int tid = threadIdx.x;
  int wave = tid >> 6, lane = tid & 63;
  int c31 = lane & 31, h = lane >> 5;
  int rb = blockIdx.x >> 4;   // 0..63
  int cg = blockIdx.x & 15;   // 0..15
  int rowbase = rb * ROWB + wave * 32;

  // A fragments: lane holds row (rowbase + c31), k-bytes m*64 + h*32 .. +31
  i32x8 a[4];
  {
    const char* ar = fb + (size_t)(rowbase + c31) * D + h * 32;
#pragma unroll
    for (int m = 0; m < 4; ++m) {
      i32x4 lo = *(const i32x4*)(ar + m * 64);
      i32x4 hi = *(const i32x4*)(ar + m * 64 + 16);
      a[m] = __builtin_shufflevector(lo, hi, 0, 1, 2, 3, 4, 5, 6, 7);
    }
  }
#pragma unroll
  for (int m = 0; m < 4; ++m)
    asm volatile("" : "+v"(a[m]));   // pin: forbid rematerialization / sinking

  float srow[16];
#pragma unroll
  for (int r = 0; r < 16; ++r) srow[r] = 0.0f;

  // staging: 256 threads x 16B x 2 passes = one 8 KB tile (32 rows x 256 B)
  int colbase = cg * COLS_PER_BLK;
  int o0 = tid * 16, o1 = o0 + 4096;
  int r0 = o0 >> 8, r1 = o1 >> 8;                 // tile row 0..31
  int g0 = (o0 & 255) ^ ((r0 & 7) << 4);          // pre-swizzled source byte
  int g1 = (o1 & 255) ^ ((r1 & 7) << 4);
  int sw = (c31 & 7) << 4;                        // read-side swizzle

#define STAGE(tt)                                                              \
  {                                                                            \
    char* stg = lds + ((tt) & (NBUF - 1)) * TILE_BYTES;                        \
    size_t cb = (size_t)(colbase + (tt) * CTILE);                              \
    gload_lds16(fb + (cb + r0) * D + g0, stg + wave * 1024);                   \
    gload_lds16(fb + (cb + r1) * D + g1, stg + 4096 + wave * 1024);            \
  }

#define COMPUTE(tt)                                                            \
  {                                                                            \
    const char* bb = lds + ((tt) & (NBUF - 1)) * TILE_BYTES + c31 * 256;       \
    f32x16 acc = {0, 0, 0, 0, 0, 0, 0, 0, 0, 0, 0, 0, 0, 0, 0, 0};            \
    _Pragma("unroll")                                                          \
    for (int m = 0; m < 4; ++m) {                                              \
      int base = m * 64 + h * 32;                                              \
      i32x4 lo = *(const i32x4*)(bb + (base ^ sw));                            \
      i32x4 hi = *(const i32x4*)(bb + ((base + 16) ^ sw));                     \
      i32x8 bv = __builtin_shufflevector(lo, hi, 0, 1, 2, 3, 4, 5, 6, 7);      \
      acc = __builtin_amdgcn_mfma_scale_f32_32x32x64_f8f6f4(                   \
          a[m], bv, acc, 0, 0, 0, 127, 0, 127);                                \
    }                                                                          \
    _Pragma("unroll")                                                          \
    for (int r = 0; r < 16; ++r) srow[r] += __expf(acc[r]);                    \
  }

  STAGE(0);
  STAGE(1);

  const int NP = NT / 2;   // 8 pairs
  for (int u = 0; u < NP; ++u) {
    asm volatile("s_waitcnt vmcnt(0)" ::: "memory");   // this pair's tiles landed
    __builtin_amdgcn_sched_barrier(0);
    __builtin_amdgcn_s_barrier();
    __builtin_amdgcn_sched_barrier(0);
    if (u + 1 < NP) {       // post-barrier staging: prev pair's buffers free
      STAGE(2 * u + 2);
      STAGE(2 * u + 3);
    }
    COMPUTE(2 * u);
    COMPUTE(2 * u + 1);
  }
#undef STAGE
#undef COMPUTE

  // reduce each row-sum across the 32 lanes (cols) sharing h
#pragma unroll
  for (int r = 0; r < 16; ++r) {
    srow[r] += __shfl_xor(srow[r], 1, 64);
    srow[r] += __shfl_xor(srow[r], 2, 64);
    srow[r] += __shfl_xor(srow[r], 4, 64);
    srow[r] += __shfl_xor(srow[r], 8, 64);
    srow[r] += __shfl_xor(srow[r], 16, 64);
  }
  if (c31 == 0) {
#pragma unroll
    for (int r = 0; r < 16; ++r) {
      int grow = rowbase + (r & 3) + 8 * (r >> 2) + 4 * h;   // C/D row mapping
      slab[(size_t)cg * N + grow] = srow[r];
    }
  }
}

// ---- kernel 3: pos-dot (fp32) + combine slab -> scalar loss ----
// 32 blocks; block b handles row pairs (r, r+4096), r in [b*128, b*128+128)
__global__ __launch_bounds__(256) void final_kernel(const float* __restrict__ feat,
                                                    const float* __restrict__ rnorm,
                                                    const float* __restrict__ slab,
                                                    float* __restrict__ out) {
  __shared__ float pl[128];
  __shared__ float r4[4];
  int tid = threadIdx.x;
  int row0 = blockIdx.x * 128;

  // phase A: pos for 128 pairs; 8 lanes per row, 32 rows per pass, 4 passes
#pragma unroll
  for (int pass = 0; pass < 4; ++pass) {
    int ri = pass * 32 + (tid >> 3);          // 0..127
    int r = row0 + ri;
    int p = r + 4096;
    int g = tid & 7;
    const float4* ra = (const float4*)(feat + (size_t)r * D);
    const float4* rb = (const float4*)(feat + (size_t)p * D);
    float d = 0.0f;
#pragma unroll
    for (int it = 0; it < 8; ++it) {
      float4 x = ra[g + it * 8], y = rb[g + it * 8];
      d += x.x * y.x + x.y * y.y + x.z * y.z + x.w * y.w;
    }
    d += __shfl_xor(d, 1, 64);
    d += __shfl_xor(d, 2, 64);
    d += __shfl_xor(d, 4, 64);
    if (g == 0) pl[ri] = d * rnorm[r] * rnorm[p];
  }
  __syncthreads();

  // phase B: 256 threads -> 256 rows (128 low + 128 high)
  int row = (tid < 128) ? (row0 + tid) : (4096 + row0 + (tid - 128));
  float ssum = 0.0f;
#pragma unroll
  for (int c = 0; c < COLG; ++c) ssum += slab[(size_t)c * N + row];
  float v = __logf(ssum - E_CONST) - pl[tid & 127];   // remove diag exp(sim_ii)~=e
  for (int m = 1; m < 64; m <<= 1) v += __shfl_xor(v, m, 64);
  if ((tid & 63) == 0) r4[tid >> 6] = v;
  __syncthreads();
  if (tid == 0) atomicAdd(out, (r4[0] + r4[1] + r4[2] + r4[3]) * (1.0f / (float)N));
}

extern "C" void kernel_launch(void* const* d_in, const int* in_sizes, int n_in,
                              void* d_out, int out_size, void* d_ws, size_t ws_size,
                              hipStream_t stream) {
  const float* feat = (const float*)d_in[0];
  unsigned char* f8 = (unsigned char*)d_ws;                                    // 2 MB
  float* rnorm = (float*)((char*)d_ws + (size_t)N * D);                        // 32 KB
  float* slab  = (float*)((char*)d_ws + (size_t)N * D + (size_t)N * 4);       // 512 KB
  float* out = (float*)d_out;

  hipMemsetAsync(out, 0, sizeof(float), stream);
  norm_kernel<<<N / 4, 256, 0, stream>>>(feat, f8, rnorm);
  simlse_kernel<<<(N / ROWB) * COLG, 256, 0, stream>>>(f8, slab);
  final_kernel<<<N / 256, 256, 0, stream>>>(feat, rnorm, slab, out);
}